// Round 3
// baseline (9992.924 us; speedup 1.0000x reference)
//
#include <hip/hip_runtime.h>

#define HID    51
#define G4     204    // 4*HID
#define EMB    7
#define VOCAB  282
#define TT     1024
#define BB     256

__device__ __forceinline__ float tanh_fast(float x) {
    return 1.0f - 2.0f / (__expf(2.0f * x) + 1.0f);
}

// LDS-only barrier: wait ds ops, DO NOT drain vmcnt (global loads are ordered by
// register deps; stores need no intra-loop visibility). Keeps eproj prefetch and
// output stores in flight across steps.
#define BAR() asm volatile("s_waitcnt lgkmcnt(0)\n\ts_barrier" ::: "memory")

// quad-lane activation + gate gather + cell update (lanes q=0..3 hold i,f,g,o)
__device__ __forceinline__ float lstm_act(float x, int q, float& c) {
    const float As = (q == 2) ? 2.f : 1.f;
    const float Bs = (q == 2) ? -1.f : 0.f;
    const float act = As / (1.f + __expf(-As * x)) + Bs;  // sigmoid or tanh
    const float v1 = __shfl_xor(act, 1);
    const float v2 = __shfl_xor(act, 2);
    const float v3 = __shfl_xor(v2, 1);
    const float t0 = (q & 1) ? v1 : act, t1 = (q & 1) ? act : v1;
    const float t2 = (q & 1) ? v3 : v2,  t3 = (q & 1) ? v2 : v3;
    const float I = (q & 2) ? t2 : t0, F = (q & 2) ? t3 : t1;
    const float G = (q & 2) ? t0 : t2, O = (q & 2) ? t1 : t3;
    const float cn = F * c + I * G;
    c = cn;
    return O * tanh_fast(cn);
}

// ---------- Kernel A: eproj[v][j] = b1[j] + sum_e embed[v][e]*w_ih1[j][e] ----------
__global__ void eproj_kernel(const float* __restrict__ embed,
                             const float* __restrict__ w_ih1,
                             const float* __restrict__ b1,
                             float* __restrict__ eproj) {
    int idx = blockIdx.x * blockDim.x + threadIdx.x;
    if (idx >= VOCAB * G4) return;
    int v = idx / G4;
    int j = idx - v * G4;
    float acc = b1[j];
    #pragma unroll
    for (int e = 0; e < EMB; e++)
        acc += embed[v * EMB + e] * w_ih1[j * EMB + e];
    eproj[idx] = acc;
}

// ---------- Kernel B: fused recurrent LSTM + output projection -------------------
// One block per batch item. 12 waves:
//   waves 0-3 (L1):  h1(s)        waves 4-7 (L2): h2(s-1)
//   waves 8-11 (OUT): logits(s-2) -> d_out directly
// One lgkm-only barrier per super-step.
__launch_bounds__(768)
__global__ void lstm_fused_kernel(const int* __restrict__ input,
                                  const float* __restrict__ eproj,
                                  const float* __restrict__ w_hh1,
                                  const float* __restrict__ w_ih2,
                                  const float* __restrict__ w_hh2,
                                  const float* __restrict__ b2,
                                  const float* __restrict__ w_lin,
                                  const float* __restrict__ b_lin,
                                  float* __restrict__ out) {
    __shared__ __align__(16) float h1b[2][52];   // 208B rows -> 13 aligned float4
    __shared__ __align__(16) float h2b[2][52];
    __shared__ int toks[TT];

    const int tid = threadIdx.x;
    const int b   = blockIdx.x;

    for (int i = tid; i < TT; i += 768) toks[i] = input[b * TT + i];
    if (tid < 52) {
        h1b[0][tid] = 0.f; h1b[1][tid] = 0.f;
        h2b[0][tid] = 0.f; h2b[1][tid] = 0.f;
    }

    const int grp = tid >> 8;          // 0=L1, 1=L2, 2=OUT
    const int lt  = tid & 255;
    // LSTM lane mapping (grp 0/1): 4 lanes per hidden elem own gates i,f,g,o
    const int  w  = lt >> 6;
    const int  l  = lt & 63;
    const int  jj = l >> 2;
    const int  q  = l & 3;
    const int  ne = (w < 3) ? 13 : 12;           // 3*13+12 = 51
    const bool al = (jj < ne);
    const int  j  = 13 * w + jj;
    const int  gs = al ? (q * 51 + j) : 0;
    // OUT mapping (grp 2): lane lt owns col lt; lanes 0..25 also own col 256+lt
    const int  col0 = lt;
    const bool has2 = (lt < 26);
    const int  col1 = has2 ? (256 + lt) : 0;

    float wA[51], wB[51];              // shared across groups -> one VGPR budget
    float bx = 0.f, by = 0.f;
    float c = 0.f;
    float ep_cur = 0.f;

    __syncthreads();                   // toks + zeroed h buffers visible

    if (grp == 0) {
        #pragma unroll
        for (int k = 0; k < 51; k++) wA[k] = w_hh1[gs * 51 + k];
        ep_cur = eproj[toks[0] * G4 + gs];
    } else if (grp == 1) {
        #pragma unroll
        for (int k = 0; k < 51; k++) { wA[k] = w_ih2[gs * 51 + k]; wB[k] = w_hh2[gs * 51 + k]; }
        bx = b2[gs];
    } else {
        #pragma unroll
        for (int k = 0; k < 51; k++) { wA[k] = w_lin[col0 * 51 + k]; wB[k] = w_lin[col1 * 51 + k]; }
        bx = b_lin[col0]; by = b_lin[col1];
    }

    const size_t obase = (size_t)b * TT;

    for (int s = 0; s <= TT + 1; ++s) {
        if (grp == 0) {
            if (s < TT) {
                const int sn = (s + 1 < TT) ? (s + 1) : 0;
                const float ep_nxt = eproj[toks[sn] * G4 + gs];   // prefetch, stays in flight
                const float4* hp = (const float4*)h1b[(s + 1) & 1];   // h1(s-1)
                float a0 = 0.f, a1 = 0.f, a2 = 0.f, a3 = 0.f;
                #pragma unroll
                for (int i = 0; i < 13; i++) {
                    float4 hv = hp[i];
                    const int k = 4 * i;
                    a0 += wA[k] * hv.x;
                    if (k + 1 < 51) a1 += wA[k + 1] * hv.y;
                    if (k + 2 < 51) a2 += wA[k + 2] * hv.z;
                    if (k + 3 < 51) a3 += wA[k + 3] * hv.w;
                }
                const float x = (a0 + a1) + (a2 + a3) + ep_cur;
                const float hn = lstm_act(x, q, c);
                if (q == 0 && al) h1b[s & 1][j] = hn;
                ep_cur = ep_nxt;
            }
        } else if (grp == 1) {
            if (s >= 1 && s <= TT) {
                const float4* hp1 = (const float4*)h1b[(s - 1) & 1];  // h1(t)
                const float4* hp2 = (const float4*)h2b[s & 1];        // h2(t-1)
                float a0 = 0.f, a1 = 0.f, a2 = 0.f, a3 = 0.f;
                #pragma unroll
                for (int i = 0; i < 13; i++) {
                    float4 ha = hp1[i];
                    float4 hb = hp2[i];
                    const int k = 4 * i;
                    a0 += wA[k] * ha.x;       a2 += wB[k] * hb.x;
                    if (k + 1 < 51) { a1 += wA[k + 1] * ha.y; a3 += wB[k + 1] * hb.y; }
                    if (k + 2 < 51) { a0 += wA[k + 2] * ha.z; a2 += wB[k + 2] * hb.z; }
                    if (k + 3 < 51) { a1 += wA[k + 3] * ha.w; a3 += wB[k + 3] * hb.w; }
                }
                const float x = (a0 + a1) + (a2 + a3) + bx;
                const float hn = lstm_act(x, q, c);
                if (q == 0 && al) h2b[(s - 1) & 1][j] = hn;
            }
        } else {
            if (s >= 2) {
                const int u = s - 2;
                const float4* hp = (const float4*)h2b[s & 1];         // h2(u)
                float a0 = 0.f, a1 = 0.f;
                #pragma unroll
                for (int i = 0; i < 13; i++) {
                    float4 hv = hp[i];
                    const int k = 4 * i;
                    a0 += wA[k] * hv.x;
                    if (k + 1 < 51) a1 += wA[k + 1] * hv.y;
                    if (k + 2 < 51) a0 += wA[k + 2] * hv.z;
                    if (k + 3 < 51) a1 += wA[k + 3] * hv.w;
                }
                out[(obase + u) * VOCAB + col0] = a0 + a1 + bx;       // coalesced per wave
                if (has2) {
                    float b0 = 0.f, b1v = 0.f;
                    #pragma unroll
                    for (int i = 0; i < 13; i++) {
                        float4 hv = hp[i];
                        const int k = 4 * i;
                        b0 += wB[k] * hv.x;
                        if (k + 1 < 51) b1v += wB[k + 1] * hv.y;
                        if (k + 2 < 51) b0  += wB[k + 2] * hv.z;
                        if (k + 3 < 51) b1v += wB[k + 3] * hv.w;
                    }
                    out[(obase + u) * VOCAB + col1] = b0 + b1v + by;
                }
            }
        }
        BAR();
    }
}

extern "C" void kernel_launch(void* const* d_in, const int* in_sizes, int n_in,
                              void* d_out, int out_size, void* d_ws, size_t ws_size,
                              hipStream_t stream) {
    const int*   input = (const int*)  d_in[0];
    const float* embed = (const float*)d_in[2];
    const float* w_ih1 = (const float*)d_in[3];
    const float* w_hh1 = (const float*)d_in[4];
    const float* b1    = (const float*)d_in[5];
    const float* w_ih2 = (const float*)d_in[6];
    const float* w_hh2 = (const float*)d_in[7];
    const float* b2    = (const float*)d_in[8];
    const float* w_lin = (const float*)d_in[9];
    const float* b_lin = (const float*)d_in[10];
    float* out   = (float*)d_out;
    float* eproj = (float*)d_ws;     // 282*204*4 = 230 KB scratch

    const int n1 = VOCAB * G4;
    eproj_kernel<<<(n1 + 255) / 256, 256, 0, stream>>>(embed, w_ih1, b1, eproj);
    lstm_fused_kernel<<<BB, 768, 0, stream>>>(input, eproj, w_hh1, w_ih2, w_hh2, b2,
                                              w_lin, b_lin, out);
}

// Round 4
// 9827.962 us; speedup vs baseline: 1.0168x; 1.0168x over previous
//
#include <hip/hip_runtime.h>

#define HID    51
#define G4     204    // 4*HID
#define EMB    7
#define VOCAB  282
#define TT     1024
#define BB     256

__device__ __forceinline__ float tanh_fast(float x) {
    return 1.0f - 2.0f / (__expf(2.0f * x) + 1.0f);
}

// LDS-only barrier: wait ds ops, DO NOT drain vmcnt (global loads are ordered by
// register deps; stores need no intra-loop visibility). Keeps eproj prefetch and
// output stores in flight across steps.
#define BAR() asm volatile("s_waitcnt lgkmcnt(0)\n\ts_barrier" ::: "memory")

// quad-lane activation + gate gather + cell update (lanes q=0..3 hold i,f,g,o)
__device__ __forceinline__ float lstm_act(float x, int q, float& c) {
    const float As = (q == 2) ? 2.f : 1.f;
    const float Bs = (q == 2) ? -1.f : 0.f;
    const float act = As / (1.f + __expf(-As * x)) + Bs;  // sigmoid or tanh
    const float v1 = __shfl_xor(act, 1);
    const float v2 = __shfl_xor(act, 2);
    const float v3 = __shfl_xor(v2, 1);
    const float t0 = (q & 1) ? v1 : act, t1 = (q & 1) ? act : v1;
    const float t2 = (q & 1) ? v3 : v2,  t3 = (q & 1) ? v2 : v3;
    const float I = (q & 2) ? t2 : t0, F = (q & 2) ? t3 : t1;
    const float G = (q & 2) ? t0 : t2, O = (q & 2) ? t1 : t3;
    const float cn = F * c + I * G;
    c = cn;
    return O * tanh_fast(cn);
}

// ---------- Kernel A: eproj[v][j] = b1[j] + sum_e embed[v][e]*w_ih1[j][e] ----------
__global__ void eproj_kernel(const float* __restrict__ embed,
                             const float* __restrict__ w_ih1,
                             const float* __restrict__ b1,
                             float* __restrict__ eproj) {
    int idx = blockIdx.x * blockDim.x + threadIdx.x;
    if (idx >= VOCAB * G4) return;
    int v = idx / G4;
    int j = idx - v * G4;
    float acc = b1[j];
    #pragma unroll
    for (int e = 0; e < EMB; e++)
        acc += embed[v * EMB + e] * w_ih1[j * EMB + e];
    eproj[idx] = acc;
}

// ---------- Kernel B: fused recurrent LSTM + output projection -------------------
// One block per batch item. 12 waves:
//   waves 0-3 (L1):  h1(s)        waves 4-7 (L2): h2(s-1)
//   waves 8-11 (OUT): logits(s-2) -> d_out directly
// One lgkm-only barrier per super-step.
// __launch_bounds__(768, 3): 3 waves/SIMD -> VGPR cap 168, enough for wA[51]+wB[51]
// in REGISTERS. Plain (768) let the compiler target 6 waves/SIMD -> 84 VGPR -> the
// weight arrays spilled to scratch -> 5 GB/dispatch of HBM spill traffic (R3).
__launch_bounds__(768, 3)
__global__ void lstm_fused_kernel(const int* __restrict__ input,
                                  const float* __restrict__ eproj,
                                  const float* __restrict__ w_hh1,
                                  const float* __restrict__ w_ih2,
                                  const float* __restrict__ w_hh2,
                                  const float* __restrict__ b2,
                                  const float* __restrict__ w_lin,
                                  const float* __restrict__ b_lin,
                                  float* __restrict__ out) {
    __shared__ __align__(16) float h1b[2][52];   // 208B rows -> 13 aligned float4
    __shared__ __align__(16) float h2b[2][52];
    __shared__ int toks[TT];

    const int tid = threadIdx.x;
    const int b   = blockIdx.x;

    for (int i = tid; i < TT; i += 768) toks[i] = input[b * TT + i];
    if (tid < 52) {
        h1b[0][tid] = 0.f; h1b[1][tid] = 0.f;
        h2b[0][tid] = 0.f; h2b[1][tid] = 0.f;
    }

    const int grp = tid >> 8;          // 0=L1, 1=L2, 2=OUT
    const int lt  = tid & 255;
    // LSTM lane mapping (grp 0/1): 4 lanes per hidden elem own gates i,f,g,o
    const int  w  = lt >> 6;
    const int  l  = lt & 63;
    const int  jj = l >> 2;
    const int  q  = l & 3;
    const int  ne = (w < 3) ? 13 : 12;           // 3*13+12 = 51
    const bool al = (jj < ne);
    const int  j  = 13 * w + jj;
    const int  gs = al ? (q * 51 + j) : 0;
    // OUT mapping (grp 2): lane lt owns col lt; lanes 0..25 also own col 256+lt
    const int  col0 = lt;
    const bool has2 = (lt < 26);
    const int  col1 = has2 ? (256 + lt) : 0;

    float wA[51], wB[51];              // shared across groups -> one VGPR budget
    float bx = 0.f, by = 0.f;
    float c = 0.f;
    float ep_cur = 0.f;

    __syncthreads();                   // toks + zeroed h buffers visible

    if (grp == 0) {
        #pragma unroll
        for (int k = 0; k < 51; k++) wA[k] = w_hh1[gs * 51 + k];
        ep_cur = eproj[toks[0] * G4 + gs];
    } else if (grp == 1) {
        #pragma unroll
        for (int k = 0; k < 51; k++) { wA[k] = w_ih2[gs * 51 + k]; wB[k] = w_hh2[gs * 51 + k]; }
        bx = b2[gs];
    } else {
        #pragma unroll
        for (int k = 0; k < 51; k++) { wA[k] = w_lin[col0 * 51 + k]; wB[k] = w_lin[col1 * 51 + k]; }
        bx = b_lin[col0]; by = b_lin[col1];
    }

    const size_t obase = (size_t)b * TT;

    for (int s = 0; s <= TT + 1; ++s) {
        if (grp == 0) {
            if (s < TT) {
                const int sn = (s + 1 < TT) ? (s + 1) : 0;
                const float ep_nxt = eproj[toks[sn] * G4 + gs];   // prefetch, stays in flight
                const float4* hp = (const float4*)h1b[(s + 1) & 1];   // h1(s-1)
                float a0 = 0.f, a1 = 0.f, a2 = 0.f, a3 = 0.f;
                #pragma unroll
                for (int i = 0; i < 13; i++) {
                    float4 hv = hp[i];
                    const int k = 4 * i;
                    a0 += wA[k] * hv.x;
                    if (k + 1 < 51) a1 += wA[k + 1] * hv.y;
                    if (k + 2 < 51) a2 += wA[k + 2] * hv.z;
                    if (k + 3 < 51) a3 += wA[k + 3] * hv.w;
                }
                const float x = (a0 + a1) + (a2 + a3) + ep_cur;
                const float hn = lstm_act(x, q, c);
                if (q == 0 && al) h1b[s & 1][j] = hn;
                ep_cur = ep_nxt;
            }
        } else if (grp == 1) {
            if (s >= 1 && s <= TT) {
                const float4* hp1 = (const float4*)h1b[(s - 1) & 1];  // h1(t)
                const float4* hp2 = (const float4*)h2b[s & 1];        // h2(t-1)
                float a0 = 0.f, a1 = 0.f, a2 = 0.f, a3 = 0.f;
                #pragma unroll
                for (int i = 0; i < 13; i++) {
                    float4 ha = hp1[i];
                    float4 hb = hp2[i];
                    const int k = 4 * i;
                    a0 += wA[k] * ha.x;       a2 += wB[k] * hb.x;
                    if (k + 1 < 51) { a1 += wA[k + 1] * ha.y; a3 += wB[k + 1] * hb.y; }
                    if (k + 2 < 51) { a0 += wA[k + 2] * ha.z; a2 += wB[k + 2] * hb.z; }
                    if (k + 3 < 51) { a1 += wA[k + 3] * ha.w; a3 += wB[k + 3] * hb.w; }
                }
                const float x = (a0 + a1) + (a2 + a3) + bx;
                const float hn = lstm_act(x, q, c);
                if (q == 0 && al) h2b[(s - 1) & 1][j] = hn;
            }
        } else {
            if (s >= 2) {
                const int u = s - 2;
                const float4* hp = (const float4*)h2b[s & 1];         // h2(u)
                float a0 = 0.f, a1 = 0.f;
                #pragma unroll
                for (int i = 0; i < 13; i++) {
                    float4 hv = hp[i];
                    const int k = 4 * i;
                    a0 += wA[k] * hv.x;
                    if (k + 1 < 51) a1 += wA[k + 1] * hv.y;
                    if (k + 2 < 51) a0 += wA[k + 2] * hv.z;
                    if (k + 3 < 51) a1 += wA[k + 3] * hv.w;
                }
                out[(obase + u) * VOCAB + col0] = a0 + a1 + bx;       // coalesced per wave
                if (has2) {
                    float b0 = 0.f, b1v = 0.f;
                    #pragma unroll
                    for (int i = 0; i < 13; i++) {
                        float4 hv = hp[i];
                        const int k = 4 * i;
                        b0 += wB[k] * hv.x;
                        if (k + 1 < 51) b1v += wB[k + 1] * hv.y;
                        if (k + 2 < 51) b0  += wB[k + 2] * hv.z;
                        if (k + 3 < 51) b1v += wB[k + 3] * hv.w;
                    }
                    out[(obase + u) * VOCAB + col1] = b0 + b1v + by;
                }
            }
        }
        BAR();
    }
}

extern "C" void kernel_launch(void* const* d_in, const int* in_sizes, int n_in,
                              void* d_out, int out_size, void* d_ws, size_t ws_size,
                              hipStream_t stream) {
    const int*   input = (const int*)  d_in[0];
    const float* embed = (const float*)d_in[2];
    const float* w_ih1 = (const float*)d_in[3];
    const float* w_hh1 = (const float*)d_in[4];
    const float* b1    = (const float*)d_in[5];
    const float* w_ih2 = (const float*)d_in[6];
    const float* w_hh2 = (const float*)d_in[7];
    const float* b2    = (const float*)d_in[8];
    const float* w_lin = (const float*)d_in[9];
    const float* b_lin = (const float*)d_in[10];
    float* out   = (float*)d_out;
    float* eproj = (float*)d_ws;     // 282*204*4 = 230 KB scratch

    const int n1 = VOCAB * G4;
    eproj_kernel<<<(n1 + 255) / 256, 256, 0, stream>>>(embed, w_ih1, b1, eproj);
    lstm_fused_kernel<<<BB, 768, 0, stream>>>(input, eproj, w_hh1, w_ih2, w_hh2, b2,
                                              w_lin, b_lin, out);
}